// Round 21
// baseline (112.793 us; speedup 1.0000x reference)
//
#include <hip/hip_runtime.h>

#define NDIM 2048
#define FDIM 64
#define KDIM 8
#define BDIM 32
#define TN   16     // tile rows (n)
#define TM   128    // tile cols (m) -> acc[8][2] = 64 VGPR (spill headroom)
#define BFROW 72    // bf16 elems per staging row (64 + 8 pad)
#define PROW  132   // f32 elems per epilogue-panel row (128 + 4)
#define PLANES 8    // b-planes per epilogue pass (R21: was 4 -> half the barriers)
#define NTILE 4     // tiles per persistent block (512 blocks = 2/CU, 1 round)

typedef __attribute__((ext_vector_type(8))) short short8;
typedef __attribute__((ext_vector_type(4))) float f32x4;

static __device__ __forceinline__ unsigned short f2bf(float x) {
    unsigned u = __float_as_uint(x);                 // RNE to bf16
    return (unsigned short)((u + 0x7fffu + ((u >> 16) & 1u)) >> 16);
}

// ---------------------------------------------------------------------------
// R21 = R20 (best PASS, 111.8us) with ONE change: PLANES 4 -> 8.
// Epilogue: 4 passes/tile x 2 barriers (half of R20's 16 barriers/tile);
// each pass scatters 8 b-planes then issues 16 NT store insts in one burst
// (longer store duty cycle between syncs). LDS: 8 panels = 67.6 KB, still
// 2 blocks/CU (<=80 KB). All R20 invariants kept: persistent 512-block grid
// (one residency round; cov bubble paid once, tile t+1 cov overlaps tile t
// stores), staged bf16 LDS cov (R17: de-staging -25us), full k-unroll
// (rule #20), SCALAR mix only (f32x4 vector-mix = miscompile R6/R7/R9),
// lgkm-only barriers (stores never drained), NT stores (R16: -5us).
// ---------------------------------------------------------------------------
__global__ __launch_bounds__(256, 2) void rfm_fused_mfma(
    const float* __restrict__ p, const float* __restrict__ L,
    const float* __restrict__ sr, float* __restrict__ out)
{
    __shared__ float pl[BDIM * KDIM];
    __shared__ __align__(16) char smem[PLANES * TN * PROW * 4];   // 67584 B

    unsigned short* const An = (unsigned short*)smem;       // [TN][BFROW] bf16
    unsigned short* const Am = An + TN * BFROW;             // [TM][BFROW] bf16

    const int t  = threadIdx.x;
    const int lane = t & 63;
    const int w   = t >> 6;        // wave 0..3: cols w*32..w*32+31
    const int l15 = lane & 15;
    const int l4  = lane >> 4;     // 0..3

    pl[t] = p[t];                  // covered by the first cov __syncthreads

    #pragma unroll 1
    for (int tt = 0; tt < NTILE; ++tt) {
        const int tile = (int)blockIdx.x + tt * 512;   // 0..2047
        const int m0 = (tile & 15) * TM;
        const int n0 = (tile >> 4) * TN;

        f32x4 acc[KDIM][2];
        #pragma unroll
        for (int k = 0; k < KDIM; ++k)
            #pragma unroll
            for (int j = 0; j < 2; ++j) acc[k][j] = (f32x4){0.f, 0.f, 0.f, 0.f};

        // ---- 1) cov phase: staged bf16 LDS + MFMA (verbatim R20) ----
        #pragma unroll
        for (int k = 0; k < KDIM; ++k) {
            const float* Lk = L + (size_t)k * (NDIM * FDIM);

            // An: 16 rows x 16 float4 (1/thread)
            {
                const int row = t >> 4;
                const int fc  = (t & 15) << 2;
                const float4 va = *(const float4*)&Lk[(size_t)(n0 + row) * FDIM + fc];
                ushort4 ua;
                ua.x = f2bf(va.x); ua.y = f2bf(va.y); ua.z = f2bf(va.z); ua.w = f2bf(va.w);
                *(ushort4*)&An[row * BFROW + fc] = ua;
            }
            // Am: 128 rows x 16 float4 = 2048 float4 (8/thread)
            #pragma unroll
            for (int r = 0; r < 8; ++r) {
                const int idx = t + r * 256;
                const int row = idx >> 4;
                const int fc  = (idx & 15) << 2;
                const float4 vb = *(const float4*)&Lk[(size_t)(m0 + row) * FDIM + fc];
                ushort4 ub;
                ub.x = f2bf(vb.x); ub.y = f2bf(vb.y); ub.z = f2bf(vb.z); ub.w = f2bf(vb.w);
                *(ushort4*)&Am[row * BFROW + fc] = ub;
            }
            __syncthreads();

            short8 af[2], bv[2][2];
            #pragma unroll
            for (int s = 0; s < 2; ++s)
                af[s] = *(const short8*)&An[l15 * BFROW + s * 32 + l4 * 8];
            #pragma unroll
            for (int j = 0; j < 2; ++j)
                #pragma unroll
                for (int s = 0; s < 2; ++s)
                    bv[j][s] = *(const short8*)
                        &Am[(w * 32 + j * 16 + l15) * BFROW + s * 32 + l4 * 8];
            #pragma unroll
            for (int j = 0; j < 2; ++j)
                #pragma unroll
                for (int s = 0; s < 2; ++s)
                    acc[k][j] = __builtin_amdgcn_mfma_f32_16x16x32_bf16(
                        af[s], bv[j][s], acc[k][j], 0, 0, 0);
            __syncthreads();   // panels consumed; next k / epilogue may reuse
        }

        // Diagonal: D row = n-local = l4*4+reg, col = m-local = w*32+j*16+l15.
        #pragma unroll
        for (int j = 0; j < 2; ++j)
            #pragma unroll
            for (int reg = 0; reg < 4; ++reg) {
                const int gn = n0 + l4 * 4 + reg;
                const int gm = m0 + w * 32 + j * 16 + l15;
                if (gn == gm) {
                    #pragma unroll
                    for (int k = 0; k < KDIM; ++k) {
                        const float q = sr[k * NDIM + gn];
                        acc[k][j][reg] += q * q;
                    }
                }
            }

        // ---- 2) epilogue: 8 planes/pass x 4 passes (NT stores) ----
        const size_t NN = (size_t)NDIM * NDIM;
        const int scr = l4 * 4;                 // scatter row base (+reg)
        const int scc = w * 32 + l15;           // scatter col base (+j*16)
        const int rbrow = t >> 5;               // readback row 0..7 (and +8)
        const int rbc4  = (t & 31) * 4;         // readback col 0..124
        float* const obase = out + (size_t)n0 * NDIM + m0 + rbc4;

        #pragma unroll 1
        for (int b = 0; b < BDIM; b += PLANES) {
            // mix (SCALAR FMAs, static acc indices) + scatter
            #pragma unroll
            for (int u = 0; u < PLANES; ++u) {
                float pb[KDIM];
                #pragma unroll
                for (int k = 0; k < KDIM; ++k) pb[k] = pl[(b + u) * KDIM + k];
                float* const Pu = (float*)smem + (size_t)u * TN * PROW;
                #pragma unroll
                for (int j = 0; j < 2; ++j)
                    #pragma unroll
                    for (int reg = 0; reg < 4; ++reg) {
                        float v = 0.0f;
                        #pragma unroll
                        for (int k = 0; k < KDIM; ++k)
                            v += pb[k] * acc[k][j][reg];
                        Pu[(scr + reg) * PROW + scc + j * 16] = v;
                    }
            }
            asm volatile("s_waitcnt lgkmcnt(0)" ::: "memory");  // ds_writes done
            __builtin_amdgcn_s_barrier();
            __builtin_amdgcn_sched_barrier(0);

            // readback + NT stores: 16 store insts in one burst
            #pragma unroll
            for (int u = 0; u < PLANES; ++u) {
                const float* const Pu = (const float*)smem + (size_t)u * TN * PROW;
                const size_t boff = (size_t)(b + u) * NN;
                #pragma unroll
                for (int rr = 0; rr < 2; ++rr) {
                    const int row = rbrow + 8 * rr;
                    const f32x4 wv = *(const f32x4*)&Pu[row * PROW + rbc4];
                    __builtin_nontemporal_store(wv,
                        (f32x4*)(obase + boff + (size_t)row * NDIM));
                }
            }
            asm volatile("s_waitcnt lgkmcnt(0)" ::: "memory");  // ds_reads done
            __builtin_amdgcn_s_barrier();            // safe to overwrite / next tile
            __builtin_amdgcn_sched_barrier(0);
        }
        // tile t+1's staging is ordered after all LDS reads by the last
        // barrier; its global NT stores remain in flight underneath.
    }
}

extern "C" void kernel_launch(void* const* d_in, const int* in_sizes, int n_in,
                              void* d_out, int out_size, void* d_ws, size_t ws_size,
                              hipStream_t stream)
{
    const float* p  = (const float*)d_in[0];   // (B,K) = (32,8)
    const float* L  = (const float*)d_in[1];   // (K,N,F) = (8,2048,64)
    const float* sr = (const float*)d_in[2];   // (K,N)   = (8,2048)
    float* out = (float*)d_out;                // (B,N,N) = (32,2048,2048)

    hipLaunchKernelGGL(rfm_fused_mfma, dim3(512), dim3(256), 0, stream,
                       p, L, sr, out);
}

// Round 22
// 108.678 us; speedup vs baseline: 1.0379x; 1.0379x over previous
//
#include <hip/hip_runtime.h>

#define NDIM 2048
#define FDIM 64
#define KDIM 8
#define BDIM 32
#define TN   16     // tile rows (n)
#define TM   128    // tile cols (m) -> acc[8][2] = 64 VGPR
#define BFROW 72    // bf16 elems per staging row (64 + 8 pad)
#define PROW  132   // f32 elems per epilogue-panel row (128 + 4)
#define PLANES 4    // b-planes per epilogue pass (R20 best; R21's 8 was flat)
#define NTILE 4     // tiles per persistent block (512 blocks = 2/CU, 1 round)

typedef __attribute__((ext_vector_type(8))) short short8;
typedef __attribute__((ext_vector_type(4))) float f32x4;

static __device__ __forceinline__ unsigned short f2bf(float x) {
    unsigned u = __float_as_uint(x);                 // RNE to bf16
    return (unsigned short)((u + 0x7fffu + ((u >> 16) & 1u)) >> 16);
}

// ---------------------------------------------------------------------------
// R22 = R20 (best PASS, 111.8us) + T14 async-STAGE split in the cov loop
// (single change): global loads for k+1 are ISSUED into registers before the
// frag-read+MFMA of k (their L2 latency hides under it); the staging at the
// top of each k is then pure ds_write of already-loaded registers. Removes
// the ~300-500cyc exposed load latency per k (x8 k x4 tiles ~ 5us/block of
// store-pipe idle). Register cost: +36 VGPR prefetch state, total ~140 --
// fine for 2 waves/SIMD (<=256); LDS unchanged 33.8 KB -> 2 blocks/CU kept.
// All R20 invariants: persistent 512-block grid, staged bf16 LDS cov, full
// k-unroll (rule #20), SCALAR mix only (f32x4 vector-mix = miscompile
// R6/R7/R9), lgkm-only barriers, NT stores.
// ---------------------------------------------------------------------------
__global__ __launch_bounds__(256, 2) void rfm_fused_mfma(
    const float* __restrict__ p, const float* __restrict__ L,
    const float* __restrict__ sr, float* __restrict__ out)
{
    __shared__ float pl[BDIM * KDIM];
    __shared__ __align__(16) char smem[PLANES * TN * PROW * 4];   // 33792 B

    unsigned short* const An = (unsigned short*)smem;       // [TN][BFROW] bf16
    unsigned short* const Am = An + TN * BFROW;             // [TM][BFROW] bf16
    float* const Parr0 = (float*)smem;                      // 4 panels [TN][PROW]
    float* const Parr1 = Parr0 + TN * PROW;
    float* const Parr2 = Parr1 + TN * PROW;
    float* const Parr3 = Parr2 + TN * PROW;

    const int t  = threadIdx.x;
    const int lane = t & 63;
    const int w   = t >> 6;        // wave 0..3: cols w*32..w*32+31
    const int l15 = lane & 15;
    const int l4  = lane >> 4;     // 0..3

    pl[t] = p[t];                  // covered by the first cov __syncthreads

    // staging addresses (constant across k and tiles except base row)
    const int sa_row = t >> 4;            // An row 0..15
    const int sa_fc  = (t & 15) << 2;     // f column (float4)

    #pragma unroll 1
    for (int tt = 0; tt < NTILE; ++tt) {
        const int tile = (int)blockIdx.x + tt * 512;   // 0..2047
        const int m0 = (tile & 15) * TM;
        const int n0 = (tile >> 4) * TN;

        f32x4 acc[KDIM][2];
        #pragma unroll
        for (int k = 0; k < KDIM; ++k)
            #pragma unroll
            for (int j = 0; j < 2; ++j) acc[k][j] = (f32x4){0.f, 0.f, 0.f, 0.f};

        // ---- cov prologue: load k=0 into registers ----
        float4 pva;
        float4 pvb[8];
        {
            const float* Lk = L;
            pva = *(const float4*)&Lk[(size_t)(n0 + sa_row) * FDIM + sa_fc];
            #pragma unroll
            for (int r = 0; r < 8; ++r) {
                const int idx = t + r * 256;
                pvb[r] = *(const float4*)
                    &Lk[(size_t)(m0 + (idx >> 4)) * FDIM + ((idx & 15) << 2)];
            }
        }

        // ---- 1) cov phase: ds_write prefetched regs -> prefetch k+1 -> MFMA
        #pragma unroll
        for (int k = 0; k < KDIM; ++k) {
            // stage current k from registers (pure ds_write)
            {
                ushort4 ua;
                ua.x = f2bf(pva.x); ua.y = f2bf(pva.y);
                ua.z = f2bf(pva.z); ua.w = f2bf(pva.w);
                *(ushort4*)&An[sa_row * BFROW + sa_fc] = ua;
            }
            #pragma unroll
            for (int r = 0; r < 8; ++r) {
                const int idx = t + r * 256;
                ushort4 ub;
                ub.x = f2bf(pvb[r].x); ub.y = f2bf(pvb[r].y);
                ub.z = f2bf(pvb[r].z); ub.w = f2bf(pvb[r].w);
                *(ushort4*)&Am[(idx >> 4) * BFROW + ((idx & 15) << 2)] = ub;
            }
            __syncthreads();

            // issue k+1 loads NOW; latency hides under frag reads + MFMA
            if (k + 1 < KDIM) {
                const float* Lk1 = L + (size_t)(k + 1) * (NDIM * FDIM);
                pva = *(const float4*)&Lk1[(size_t)(n0 + sa_row) * FDIM + sa_fc];
                #pragma unroll
                for (int r = 0; r < 8; ++r) {
                    const int idx = t + r * 256;
                    pvb[r] = *(const float4*)
                        &Lk1[(size_t)(m0 + (idx >> 4)) * FDIM + ((idx & 15) << 2)];
                }
            }

            short8 af[2], bv[2][2];
            #pragma unroll
            for (int s = 0; s < 2; ++s)
                af[s] = *(const short8*)&An[l15 * BFROW + s * 32 + l4 * 8];
            #pragma unroll
            for (int j = 0; j < 2; ++j)
                #pragma unroll
                for (int s = 0; s < 2; ++s)
                    bv[j][s] = *(const short8*)
                        &Am[(w * 32 + j * 16 + l15) * BFROW + s * 32 + l4 * 8];
            #pragma unroll
            for (int j = 0; j < 2; ++j)
                #pragma unroll
                for (int s = 0; s < 2; ++s)
                    acc[k][j] = __builtin_amdgcn_mfma_f32_16x16x32_bf16(
                        af[s], bv[j][s], acc[k][j], 0, 0, 0);
            __syncthreads();   // panels consumed; next k / epilogue may reuse
        }

        // Diagonal: D row = n-local = l4*4+reg, col = m-local = w*32+j*16+l15.
        #pragma unroll
        for (int j = 0; j < 2; ++j)
            #pragma unroll
            for (int reg = 0; reg < 4; ++reg) {
                const int gn = n0 + l4 * 4 + reg;
                const int gm = m0 + w * 32 + j * 16 + l15;
                if (gn == gm) {
                    #pragma unroll
                    for (int k = 0; k < KDIM; ++k) {
                        const float q = sr[k * NDIM + gn];
                        acc[k][j][reg] += q * q;
                    }
                }
            }

        // ---- 2) epilogue: 4 planes/pass x 8 passes (verbatim R20) ----
        const size_t NN = (size_t)NDIM * NDIM;
        float* const Parr[PLANES] = { Parr0, Parr1, Parr2, Parr3 };
        const int scr = l4 * 4;                 // scatter row base (+reg)
        const int scc = w * 32 + l15;           // scatter col base (+j*16)
        const int rbrow = t >> 5;               // readback row 0..7 (and +8)
        const int rbc4  = (t & 31) * 4;         // readback col 0..124
        float* const obase = out + (size_t)n0 * NDIM + m0 + rbc4;

        #pragma unroll 1
        for (int b = 0; b < BDIM; b += PLANES) {
            #pragma unroll
            for (int u = 0; u < PLANES; ++u) {
                float pb[KDIM];
                #pragma unroll
                for (int k = 0; k < KDIM; ++k) pb[k] = pl[(b + u) * KDIM + k];
                float* const Pu = Parr[u];
                #pragma unroll
                for (int j = 0; j < 2; ++j)
                    #pragma unroll
                    for (int reg = 0; reg < 4; ++reg) {
                        float v = 0.0f;
                        #pragma unroll
                        for (int k = 0; k < KDIM; ++k)
                            v += pb[k] * acc[k][j][reg];
                        Pu[(scr + reg) * PROW + scc + j * 16] = v;
                    }
            }
            asm volatile("s_waitcnt lgkmcnt(0)" ::: "memory");  // ds_writes done
            __builtin_amdgcn_s_barrier();
            __builtin_amdgcn_sched_barrier(0);

            #pragma unroll
            for (int u = 0; u < PLANES; ++u) {
                const float* const Pu = Parr[u];
                const size_t boff = (size_t)(b + u) * NN;
                #pragma unroll
                for (int rr = 0; rr < 2; ++rr) {
                    const int row = rbrow + 8 * rr;
                    const f32x4 wv = *(const f32x4*)&Pu[row * PROW + rbc4];
                    __builtin_nontemporal_store(wv,
                        (f32x4*)(obase + boff + (size_t)row * NDIM));
                }
            }
            asm volatile("s_waitcnt lgkmcnt(0)" ::: "memory");  // ds_reads done
            __builtin_amdgcn_s_barrier();            // safe to overwrite / next tile
            __builtin_amdgcn_sched_barrier(0);
        }
    }
}

extern "C" void kernel_launch(void* const* d_in, const int* in_sizes, int n_in,
                              void* d_out, int out_size, void* d_ws, size_t ws_size,
                              hipStream_t stream)
{
    const float* p  = (const float*)d_in[0];   // (B,K) = (32,8)
    const float* L  = (const float*)d_in[1];   // (K,N,F) = (8,2048,64)
    const float* sr = (const float*)d_in[2];   // (K,N)   = (8,2048)
    float* out = (float*)d_out;                // (B,N,N) = (32,2048,2048)

    hipLaunchKernelGGL(rfm_fused_mfma, dim3(512), dim3(256), 0, stream,
                       p, L, sr, out);
}